// Round 8
// baseline (97.140 us; speedup 1.0000x reference)
//
#include <hip/hip_runtime.h>

// src (B,C,D,H,W) f32, flow (B,3,D,H,W) f32, C==1
constexpr int B  = 2;
constexpr int D  = 160;
constexpr int H  = 192;
constexpr int W  = 224;
constexpr int HW = H * W;        // 43008
constexpr int N  = D * HW;       // 6,881,280 per volume

// Block tile 32x * 8y * 8z = 2048 voxels, 256 threads, 8 voxels/thread.
// LDS slab = tile + halo 4 on each side (covers |flow|<4; global fallback else)
constexpr int TX = 32, TY = 8, TZ = 8;
constexpr int HALO = 4;
constexpr int SLX = TX + 2 * HALO;   // 40
constexpr int SLY = TY + 2 * HALO;   // 16
constexpr int SLZ = TZ + 2 * HALO;   // 16
constexpr int SLAB = SLX * SLY * SLZ;        // 10240 floats = 40 KiB
constexpr int GX = W / TX;   // 7
constexpr int GY = H / TY;   // 24
constexpr int GZ = D / TZ;   // 20
constexpr int NBLOCKS = GX * GY * GZ * B;    // 6720

typedef float f2 __attribute__((ext_vector_type(2)));
struct __attribute__((packed, aligned(4))) f2u { f2 v; };

__global__ __launch_bounds__(256) void st3d_warp_v6(
    const float* __restrict__ src,
    const float* __restrict__ flow,
    float* __restrict__ out)
{
    __shared__ float lds[SLAB];

    const int tid = threadIdx.x;
    int tmp = blockIdx.x;
    const int bx = tmp % GX; tmp /= GX;
    const int by = tmp % GY; tmp /= GY;
    const int bz = tmp % GZ;
    const int b  = tmp / GZ;

    const int xb = bx * TX, yb = by * TY, zb = bz * TZ;
    const int xlo = xb - HALO, ylo = yb - HALO, zlo = zb - HALO;

    const int x = xb + (tid & 31);
    const int y = yb + (tid >> 5);           // [0,8)

    const float* fl = flow + (size_t)b * 3 * N;
    const float* sb = src  + (size_t)b * N;   // C == 1

    // ---- flow preload (24 independent loads, in flight during staging) ----
    float fzv[TZ], fyv[TZ], fxv[TZ];
    const int n0 = zb * HW + y * W + x;
#pragma unroll
    for (int j = 0; j < TZ; ++j) {
        int n = n0 + j * HW;
        fzv[j] = fl[n];
        fyv[j] = fl[N + n];
        fxv[j] = fl[2 * N + n];
    }

    // ---- stage slab: 2560 float4, 10 per thread, value = src[clamped idx] ----
    // x is float4-aligned (HALO*4B = 16B); x-edge clamp via splat selects.
#pragma unroll
    for (int k = 0; k < SLAB / 4 / 256; ++k) {   // 10
        int s4  = k * 256 + tid;                 // [0,2560)
        int q   = s4 / 10;                       // slab row (sz*16+sy)
        int sx4 = s4 - q * 10;
        int sz  = q >> 4;
        int sy  = q & 15;
        int gz  = min(max(zlo + sz, 0), D - 1);
        int gy  = min(max(ylo + sy, 0), H - 1);
        int gx0 = xlo + sx4 * 4;
        int gxc = min(max(gx0, 0), W - 4);
        float4 v = *reinterpret_cast<const float4*>(sb + gz * HW + gy * W + gxc);
        if (gx0 < 0)          v = make_float4(v.x, v.x, v.x, v.x);   // all clamp to col 0
        else if (gx0 > W - 4) v = make_float4(v.w, v.w, v.w, v.w);   // all clamp to col W-1
        *reinterpret_cast<float4*>(&lds[q * SLX + sx4 * 4]) = v;
    }
    __syncthreads();

    // ---- per-voxel compute: 8 z-planes per thread ----
#pragma unroll
    for (int j = 0; j < TZ; ++j) {
        int z = zb + j;
        float cz = (float)z + fzv[j];
        float cy = (float)y + fyv[j];
        float cx = (float)x + fxv[j];

        float fz0 = floorf(cz); int z0 = (int)fz0; float fz = cz - fz0;
        float fy0 = floorf(cy); int y0 = (int)fy0; float fy = cy - fy0;
        float fx0 = floorf(cx); int x0 = (int)fx0; float fx = cx - fx0;
        int z1 = z0 + 1, y1 = y0 + 1, x1 = x0 + 1;

        float wz0 = (1.0f - fz) * ((z0 >= 0 && z0 < D) ? 1.0f : 0.0f);
        float wz1 = fz          * ((z1 >= 0 && z1 < D) ? 1.0f : 0.0f);
        float wy0 = (1.0f - fy) * ((y0 >= 0 && y0 < H) ? 1.0f : 0.0f);
        float wy1 = fy          * ((y1 >= 0 && y1 < H) ? 1.0f : 0.0f);
        float wx0 = (1.0f - fx) * ((x0 >= 0 && x0 < W) ? 1.0f : 0.0f);
        float wx1 = fx          * ((x1 >= 0 && x1 < W) ? 1.0f : 0.0f);

        // x-pair base (one 2-float read covers both x corners; edge cases
        // carry weight 0, verified per-case as in v4)
        int  xp   = min(max(x0, 0), W - 2);
        bool sel0 = (x0 == xp);
        bool sel1 = (x0 <  xp);

        int zc0 = min(max(z0, 0), D - 1), zc1 = min(max(z1, 0), D - 1);
        int yc0 = min(max(y0, 0), H - 1), yc1 = min(max(y1, 0), H - 1);

        // clamped indices inside slab? (exact test on the looked-up indices)
        bool in_slab = (zc0 >= zlo) & (zc1 <= zlo + SLZ - 1)
                     & (yc0 >= ylo) & (yc1 <= ylo + SLY - 1)
                     & (xp  >= xlo) & (xp  <= xlo + SLX - 2);

        float p00x, p00y, p01x, p01y, p10x, p10y, p11x, p11y;
        if (in_slab) {
            int lz0 = zc0 - zlo, lz1 = zc1 - zlo;
            int ly0 = yc0 - ylo, ly1 = yc1 - ylo;
            int lx  = xp  - xlo;
            int i00 = (lz0 * SLY + ly0) * SLX + lx;
            int i01 = (lz0 * SLY + ly1) * SLX + lx;
            int i10 = (lz1 * SLY + ly0) * SLX + lx;
            int i11 = (lz1 * SLY + ly1) * SLX + lx;
            p00x = lds[i00]; p00y = lds[i00 + 1];
            p01x = lds[i01]; p01y = lds[i01 + 1];
            p10x = lds[i10]; p10y = lds[i10 + 1];
            p11x = lds[i11]; p11y = lds[i11 + 1];
        } else {
            // rare (|flow| >= ~4): direct global gather, same values
            f2 t00 = ((const f2u*)(sb + zc0 * HW + yc0 * W + xp))->v;
            f2 t01 = ((const f2u*)(sb + zc0 * HW + yc1 * W + xp))->v;
            f2 t10 = ((const f2u*)(sb + zc1 * HW + yc0 * W + xp))->v;
            f2 t11 = ((const f2u*)(sb + zc1 * HW + yc1 * W + xp))->v;
            p00x = t00.x; p00y = t00.y;
            p01x = t01.x; p01y = t01.y;
            p10x = t10.x; p10y = t10.y;
            p11x = t11.x; p11y = t11.y;
        }

        float f00 = (sel0 ? p00x : p00y) * wx0 + (sel1 ? p00x : p00y) * wx1;
        float f01 = (sel0 ? p01x : p01y) * wx0 + (sel1 ? p01x : p01y) * wx1;
        float f10 = (sel0 ? p10x : p10y) * wx0 + (sel1 ? p10x : p10y) * wx1;
        float f11 = (sel0 ? p11x : p11y) * wx0 + (sel1 ? p11x : p11y) * wx1;

        float acc = wz0 * (wy0 * f00 + wy1 * f01)
                  + wz1 * (wy0 * f10 + wy1 * f11);

        out[(size_t)b * N + z * HW + y * W + x] = acc;
    }
}

extern "C" void kernel_launch(void* const* d_in, const int* in_sizes, int n_in,
                              void* d_out, int out_size, void* d_ws, size_t ws_size,
                              hipStream_t stream)
{
    const float* src  = (const float*)d_in[0];
    const float* flow = (const float*)d_in[1];
    float* out = (float*)d_out;

    st3d_warp_v6<<<NBLOCKS, 256, 0, stream>>>(src, flow, out);
}